// Round 1
// baseline (929.238 us; speedup 1.0000x reference)
//
#include <hip/hip_runtime.h>
#include <stdint.h>

#define NB   8
#define TOK  4096
#define DIM  512
#define HALF 2048
#define RR   1024

typedef unsigned long long u64;
typedef unsigned int u32;

// order-preserving f32 -> u32 mapping (monotone increasing)
__device__ __forceinline__ u32 mono_f32(float f) {
    u32 u = __float_as_uint(f);
    return (u & 0x80000000u) ? ~u : (u | 0x80000000u);
}

// ---------------- K0: init atomically-updated ws arrays ----------------
__global__ void k_init(u64* __restrict__ best, u64* __restrict__ wkey) {
    int i = blockIdx.x * 256 + threadIdx.x;
    if (i < NB * HALF) { best[i] = 0ull; wkey[i] = ~0ull; }
}

// ---------------- K1: per-token inverse norms ----------------
__global__ void k_norms(const float* __restrict__ x, float* __restrict__ invn) {
    int row  = blockIdx.x * 4 + (threadIdx.x >> 6);
    int lane = threadIdx.x & 63;
    const float* p = x + (size_t)row * DIM + 4 * lane;
    float4 v0 = *(const float4*)p;
    float4 v1 = *(const float4*)(p + 256);
    float ss = v0.x*v0.x + v0.y*v0.y + v0.z*v0.z + v0.w*v0.w
             + v1.x*v1.x + v1.y*v1.y + v1.z*v1.z + v1.w*v1.w;
#pragma unroll
    for (int m = 32; m; m >>= 1) ss += __shfl_xor(ss, m, 64);
    if (lane == 0) invn[row] = 1.0f / fmaxf(sqrtf(ss), 1e-12f);
}

// ---------------- K2: fused scores GEMM + row max/argmax ----------------
// scores[s,t] = dot(x[2s+1], x[2t]) * invn[2s+1] * invn[2t]
// best[b][s]  = max-key over t of (mono(score)<<32 | 2047-t)  (tie -> smaller t)
__launch_bounds__(256)
__global__ void k_scores(const float* __restrict__ x, const float* __restrict__ invn,
                         u64* __restrict__ best) {
    __shared__ float As[32][128];
    __shared__ float Bs[32][128];
    int bx = blockIdx.x;
    int b  = bx >> 8;
    int im = (bx >> 4) & 15;
    int in = bx & 15;
    const float* xb = x + (size_t)b * TOK * DIM;
    int tid = threadIdx.x;
    int tx = tid & 15, ty = tid >> 4;

    float acc[8][8];
#pragma unroll
    for (int i = 0; i < 8; ++i)
#pragma unroll
        for (int j = 0; j < 8; ++j) acc[i][j] = 0.f;

    for (int kt = 0; kt < DIM; kt += 32) {
#pragma unroll
        for (int i = 0; i < 4; ++i) {
            int gid = tid + 256 * i;
            int m = gid & 127, kc = gid >> 7;
            float4 a = *(const float4*)(xb + (size_t)(2*(im*128 + m) + 1) * DIM + kt + 4*kc);
            float4 v = *(const float4*)(xb + (size_t)(2*(in*128 + m)    ) * DIM + kt + 4*kc);
            As[4*kc+0][m] = a.x; As[4*kc+1][m] = a.y; As[4*kc+2][m] = a.z; As[4*kc+3][m] = a.w;
            Bs[4*kc+0][m] = v.x; Bs[4*kc+1][m] = v.y; Bs[4*kc+2][m] = v.z; Bs[4*kc+3][m] = v.w;
        }
        __syncthreads();
#pragma unroll
        for (int kk = 0; kk < 32; ++kk) {
            float a[8], bb[8];
            *(float4*)(a)    = *(const float4*)&As[kk][4*ty];
            *(float4*)(a+4)  = *(const float4*)&As[kk][64 + 4*ty];
            *(float4*)(bb)   = *(const float4*)&Bs[kk][4*tx];
            *(float4*)(bb+4) = *(const float4*)&Bs[kk][64 + 4*tx];
#pragma unroll
            for (int i = 0; i < 8; ++i)
#pragma unroll
                for (int j = 0; j < 8; ++j)
                    acc[i][j] = fmaf(a[i], bb[j], acc[i][j]);
        }
        __syncthreads();
    }

    float invd[8];
#pragma unroll
    for (int j = 0; j < 8; ++j) {
        int cloc = (j < 4) ? (4*tx + j) : (64 + 4*tx + j - 4);
        invd[j] = invn[(size_t)b * TOK + 2*(in*128 + cloc)];
    }
#pragma unroll
    for (int i = 0; i < 8; ++i) {
        int rloc = (i < 4) ? (4*ty + i) : (64 + 4*ty + i - 4);
        int s = im*128 + rloc;
        float invs = invn[(size_t)b * TOK + 2*s + 1];
        u64 key = 0;
#pragma unroll
        for (int j = 0; j < 8; ++j) {
            int cloc = (j < 4) ? (4*tx + j) : (64 + 4*tx + j - 4);
            int t = in*128 + cloc;
            float sc = acc[i][j] * invs * invd[j];
            u64 k = ((u64)mono_f32(sc) << 32) | (u32)(2047 - t);
            key = (key > k) ? key : k;
        }
        // reduce across the 16 tx-lanes sharing this row
#pragma unroll
        for (int m = 1; m < 16; m <<= 1) {
            u32 lo = (u32)key, hi = (u32)(key >> 32);
            lo = __shfl_xor(lo, m, 64);
            hi = __shfl_xor(hi, m, 64);
            u64 o = ((u64)hi << 32) | lo;
            key = (key > o) ? key : o;
        }
        if (tx == 0) atomicMax(&best[b*HALF + s], key);
    }
}

// ---------------- K3: top-k membership + duplicate-dst winner ----------------
// rank by (score desc, s asc); member iff rank < R.
// winner per dst = LAST update in top_src order = min composite key (atomicMin).
__global__ void k_topk(const u64* __restrict__ best, u64* __restrict__ wkey,
                       u32* __restrict__ member, u32* __restrict__ dstmap) {
    __shared__ u32 smono[HALF];
    int b = blockIdx.x, tid = threadIdx.x;
    u32 myDst[2];
#pragma unroll
    for (int q = 0; q < 2; ++q) {
        int s = tid + q * 1024;
        u64 k = best[b*HALF + s];
        smono[s] = (u32)(k >> 32);
        u32 d = 2047u - (u32)(k & 0xffffffffu);
        myDst[q] = d;
        dstmap[b*HALF + s] = d;
    }
    __syncthreads();
#pragma unroll
    for (int q = 0; q < 2; ++q) {
        int s = tid + q * 1024;
        u32 ms = smono[s];
        int rank = 0;
        for (int t = 0; t < HALF; ++t) {
            u32 mt = smono[t];
            rank += ((mt > ms) || (mt == ms && t < s)) ? 1 : 0;
        }
        u32 mem = (rank < RR) ? 1u : 0u;
        member[b*HALF + s] = mem;
        if (mem) {
            u64 key = ((u64)ms << 32) | (u32)(2047 - s);
            atomicMin(&wkey[b*HALF + myDst[q]], key);
        }
    }
}

// ---------------- K5: y = x_out @ W + b  (merge fused into A-loader) ----------------
__launch_bounds__(256)
__global__ void k_out(const float* __restrict__ x, const float* __restrict__ W,
                      const float* __restrict__ bias, const u64* __restrict__ wkey,
                      float* __restrict__ out) {
    __shared__ float As[32][128];
    __shared__ float Bs[32][128];
    int bx = blockIdx.x;
    int im = bx >> 2, in = bx & 3;
    int tid = threadIdx.x, tx = tid & 15, ty = tid >> 4;

    float acc[8][8];
#pragma unroll
    for (int i = 0; i < 8; ++i)
#pragma unroll
        for (int j = 0; j < 8; ++j) acc[i][j] = 0.f;

    for (int kt = 0; kt < DIM; kt += 32) {
#pragma unroll
        for (int i = 0; i < 4; ++i) {
            int gid = tid + 256 * i;
            int m = gid & 127, kc = gid >> 7;
            int g = im*128 + m;
            int t = g & (TOK - 1), b = g >> 12;
            float4 a = *(const float4*)(x + (size_t)g * DIM + kt + 4*kc);
            if (!(t & 1)) {
                u64 wk = wkey[b*HALF + (t >> 1)];
                if (wk != ~0ull) {
                    int s = 2047 - (int)(wk & 0xffffffffu);
                    float4 u = *(const float4*)(x + ((size_t)b*TOK + 2*s + 1) * DIM + kt + 4*kc);
                    a.x = (a.x + u.x) * 0.5f;
                    a.y = (a.y + u.y) * 0.5f;
                    a.z = (a.z + u.z) * 0.5f;
                    a.w = (a.w + u.w) * 0.5f;
                }
            }
            As[4*kc+0][m] = a.x; As[4*kc+1][m] = a.y; As[4*kc+2][m] = a.z; As[4*kc+3][m] = a.w;
        }
#pragma unroll
        for (int i = 0; i < 4; ++i) {
            int gid = tid + 256 * i;
            int n4 = gid & 31, k = gid >> 5;
            float4 w = *(const float4*)(W + (size_t)(kt + k) * DIM + in*128 + 4*n4);
            *(float4*)&Bs[k][4*n4] = w;
        }
        __syncthreads();
#pragma unroll
        for (int kk = 0; kk < 32; ++kk) {
            float a[8], bb[8];
            *(float4*)(a)    = *(const float4*)&As[kk][4*ty];
            *(float4*)(a+4)  = *(const float4*)&As[kk][64 + 4*ty];
            *(float4*)(bb)   = *(const float4*)&Bs[kk][4*tx];
            *(float4*)(bb+4) = *(const float4*)&Bs[kk][64 + 4*tx];
#pragma unroll
            for (int i = 0; i < 8; ++i)
#pragma unroll
                for (int j = 0; j < 8; ++j)
                    acc[i][j] = fmaf(a[i], bb[j], acc[i][j]);
        }
        __syncthreads();
    }

    float bcol[8];
#pragma unroll
    for (int j = 0; j < 8; ++j) {
        int cloc = (j < 4) ? (4*tx + j) : (64 + 4*tx + j - 4);
        bcol[j] = bias[in*128 + cloc];
    }
#pragma unroll
    for (int i = 0; i < 8; ++i) {
        int rloc = (i < 4) ? (4*ty + i) : (64 + 4*ty + i - 4);
        int g = im*128 + rloc;
        float4 v0 = { acc[i][0] + bcol[0], acc[i][1] + bcol[1],
                      acc[i][2] + bcol[2], acc[i][3] + bcol[3] };
        float4 v1 = { acc[i][4] + bcol[4], acc[i][5] + bcol[5],
                      acc[i][6] + bcol[6], acc[i][7] + bcol[7] };
        *(float4*)(out + (size_t)g * DIM + in*128 + 4*tx)      = v0;
        *(float4*)(out + (size_t)g * DIM + in*128 + 64 + 4*tx) = v1;
    }
}

// ---------------- K6: merged src rows copy their dst's hidden row ----------------
__global__ void k_fix(const u32* __restrict__ member, const u32* __restrict__ dstmap,
                      float* __restrict__ out) {
    int idx = blockIdx.x;
    if (!member[idx]) return;
    int b = idx >> 11, s = idx & (HALF - 1);
    const float* sp = out + ((size_t)b * TOK + 2 * (size_t)dstmap[idx]) * DIM;
    float*       dp = out + ((size_t)b * TOK + 2 * (size_t)s + 1) * DIM;
    int l = threadIdx.x;
    *(float4*)(dp + 4*l) = *(const float4*)(sp + 4*l);
}

extern "C" void kernel_launch(void* const* d_in, const int* in_sizes, int n_in,
                              void* d_out, int out_size, void* d_ws, size_t ws_size,
                              hipStream_t stream) {
    const float* x    = (const float*)d_in[0];
    const float* W    = (const float*)d_in[1];
    const float* bias = (const float*)d_in[2];
    float* out = (float*)d_out;

    char* ws = (char*)d_ws;
    float* invn   = (float*)(ws);               // 32768 f32  = 128 KB
    u64*   best   = (u64*)(ws + (128 << 10));   // 16384 u64  = 128 KB
    u64*   wkey   = (u64*)(ws + (256 << 10));   // 16384 u64  = 128 KB
    u32*   dstmap = (u32*)(ws + (384 << 10));   // 16384 u32  =  64 KB
    u32*   member = (u32*)(ws + (448 << 10));   // 16384 u32  =  64 KB

    hipLaunchKernelGGL(k_init,   dim3(64),    dim3(256),  0, stream, best, wkey);
    hipLaunchKernelGGL(k_norms,  dim3(8192),  dim3(256),  0, stream, x, invn);
    hipLaunchKernelGGL(k_scores, dim3(2048),  dim3(256),  0, stream, x, invn, best);
    hipLaunchKernelGGL(k_topk,   dim3(NB),    dim3(1024), 0, stream, best, wkey, member, dstmap);
    hipLaunchKernelGGL(k_out,    dim3(1024),  dim3(256),  0, stream, x, W, bias, wkey, out);
    hipLaunchKernelGGL(k_fix,    dim3(16384), dim3(128),  0, stream, member, dstmap, out);
}

// Round 3
// 500.113 us; speedup vs baseline: 1.8581x; 1.8581x over previous
//
#include <hip/hip_runtime.h>
#include <stdint.h>

#define NB   8
#define TOK  4096
#define DIM  512
#define HALF 2048
#define RR   1024

typedef unsigned long long u64;
typedef unsigned int u32;
typedef _Float16 f16;
typedef f16 f16x8 __attribute__((ext_vector_type(8)));
typedef float f32x4 __attribute__((ext_vector_type(4)));

__device__ __forceinline__ u32 mono_f32(float f) {
    u32 u = __float_as_uint(f);
    return (u & 0x80000000u) ? ~u : (u | 0x80000000u);
}
__device__ __forceinline__ u64 umax64(u64 a, u64 b) { return a > b ? a : b; }

// ---------------- K0: init atomically-updated ws arrays ----------------
__global__ void k_init(u64* __restrict__ best, u64* __restrict__ wkey) {
    int i = blockIdx.x * 256 + threadIdx.x;
    if (i < NB * HALF) { best[i] = 0ull; wkey[i] = ~0ull; }
}

// ---------------- split x -> fp16 hi/lo (exact: x = h + l + eps(2^-22)) ----------------
__global__ void k_split(const float* __restrict__ x, f16* __restrict__ xh, f16* __restrict__ xl) {
    size_t i = (size_t)blockIdx.x * 256 + threadIdx.x;   // 2,097,152 threads x 8 elems
    const float4* p = (const float4*)(x + i * 8);
    float4 a = p[0], b = p[1];
    float va[8] = {a.x, a.y, a.z, a.w, b.x, b.y, b.z, b.w};
    f16x8 h, l;
#pragma unroll
    for (int e = 0; e < 8; ++e) {
        f16 hh = (f16)va[e];
        h[e] = hh;
        l[e] = (f16)(va[e] - (float)hh);
    }
    *(f16x8*)(xh + i * 8) = h;
    *(f16x8*)(xl + i * 8) = l;
}

// ---------------- split + transpose W -> Wh_t/Wl_t [n][k] ----------------
__global__ void k_wsplit(const float* __restrict__ W, f16* __restrict__ Wh, f16* __restrict__ Wl) {
    int k = blockIdx.x;
    for (int n = threadIdx.x; n < DIM; n += 256) {
        float v = W[(size_t)k * DIM + n];
        f16 h = (f16)v;
        Wh[(size_t)n * DIM + k] = h;
        Wl[(size_t)n * DIM + k] = (f16)(v - (float)h);
    }
}

// ---------------- per-token inverse norms ----------------
__global__ void k_norms(const float* __restrict__ x, float* __restrict__ invn) {
    int row  = blockIdx.x * 4 + (threadIdx.x >> 6);
    int lane = threadIdx.x & 63;
    const float* p = x + (size_t)row * DIM + 4 * lane;
    float4 v0 = *(const float4*)p;
    float4 v1 = *(const float4*)(p + 256);
    float ss = v0.x*v0.x + v0.y*v0.y + v0.z*v0.z + v0.w*v0.w
             + v1.x*v1.x + v1.y*v1.y + v1.z*v1.z + v1.w*v1.w;
#pragma unroll
    for (int m = 32; m; m >>= 1) ss += __shfl_xor(ss, m, 64);
    if (lane == 0) invn[row] = 1.0f / fmaxf(sqrtf(ss), 1e-12f);
}

// ---------------- fused scores GEMM (fp16 3-term split MFMA) + row max/argmax ----------------
// K-logical = 3*512: thirds (hA,hB), (lA,hB), (hA,lB). BK=64 -> 24 steps.
__launch_bounds__(256)
__global__ void k_scores(const f16* __restrict__ xh, const f16* __restrict__ xl,
                         const float* __restrict__ invn, u64* __restrict__ best) {
    __shared__ f16 As[8][128][8];   // [kchunk][row][8 halfs] = 16 KB
    __shared__ f16 Bs[8][128][8];
    int bx = blockIdx.x;
    int b = bx >> 8, sb = (bx >> 4) & 15, tb = bx & 15;
    int tid = threadIdx.x, lane = tid & 63, w = tid >> 6, wr = w >> 1, wc = w & 1;
    int cc = lane >> 4, rm = lane & 15;

    f32x4 acc[4][4];
#pragma unroll
    for (int i = 0; i < 4; ++i)
#pragma unroll
        for (int j = 0; j < 4; ++j) acc[i][j] = (f32x4){0.f, 0.f, 0.f, 0.f};

    size_t rowA[4], rowB[4];
#pragma unroll
    for (int r = 0; r < 4; ++r) {
        int g = tid + 256 * r, c = g >> 7, m = g & 127;
        rowA[r] = ((size_t)b * TOK + 2 * (sb * 128 + m) + 1) * DIM + c * 8;
        rowB[r] = ((size_t)b * TOK + 2 * (tb * 128 + m)    ) * DIM + c * 8;
    }
    f16x8 pa[4], pb[4];
#pragma unroll
    for (int r = 0; r < 4; ++r) { pa[r] = *(const f16x8*)(xh + rowA[r]); pb[r] = *(const f16x8*)(xh + rowB[r]); }

    for (int ks = 0; ks < 24; ++ks) {
        __syncthreads();
#pragma unroll
        for (int r = 0; r < 4; ++r) {
            int g = tid + 256 * r;
            *(f16x8*)(&As[0][0][0] + (size_t)g * 8) = pa[r];
            *(f16x8*)(&Bs[0][0][0] + (size_t)g * 8) = pb[r];
        }
        __syncthreads();
        if (ks < 23) {
            int kn = ks + 1, third = kn >> 3, col0 = (kn & 7) << 6;
            const f16* Aa = (third == 1) ? xl : xh;
            const f16* Ba = (third == 2) ? xl : xh;
#pragma unroll
            for (int r = 0; r < 4; ++r) {
                pa[r] = *(const f16x8*)(Aa + rowA[r] + col0);
                pb[r] = *(const f16x8*)(Ba + rowB[r] + col0);
            }
        }
#pragma unroll
        for (int kk = 0; kk < 2; ++kk) {
            f16x8 af[4], bf[4];
            int ch = kk * 4 + cc;
#pragma unroll
            for (int f = 0; f < 4; ++f) {
                af[f] = *(const f16x8*)&As[ch][wr * 64 + f * 16 + rm][0];
                bf[f] = *(const f16x8*)&Bs[ch][wc * 64 + f * 16 + rm][0];
            }
#pragma unroll
            for (int i = 0; i < 4; ++i)
#pragma unroll
                for (int j = 0; j < 4; ++j)
                    acc[i][j] = __builtin_amdgcn_mfma_f32_16x16x32_f16(af[i], bf[j], acc[i][j], 0, 0, 0);
        }
    }

    float invd[4];
#pragma unroll
    for (int j = 0; j < 4; ++j) {
        int t = tb * 128 + wc * 64 + j * 16 + rm;
        invd[j] = invn[(size_t)b * TOK + 2 * t];
    }
#pragma unroll
    for (int i = 0; i < 4; ++i) {
#pragma unroll
        for (int r = 0; r < 4; ++r) {
            int s = sb * 128 + wr * 64 + i * 16 + cc * 4 + r;   // C row = (lane>>4)*4 + reg
            float invs = invn[(size_t)b * TOK + 2 * s + 1];
            u64 key = 0;
#pragma unroll
            for (int j = 0; j < 4; ++j) {
                int t = tb * 128 + wc * 64 + j * 16 + rm;       // C col = lane&15
                float sc = acc[i][j][r] * invs * invd[j];
                u64 k = ((u64)mono_f32(sc) << 32) | (u32)(2047 - t);
                key = umax64(key, k);
            }
#pragma unroll
            for (int m = 1; m < 16; m <<= 1) {
                u32 lo = (u32)key, hi = (u32)(key >> 32);
                lo = __shfl_xor(lo, m, 64);
                hi = __shfl_xor(hi, m, 64);
                key = umax64(key, ((u64)hi << 32) | lo);
            }
            if (rm == 0) atomicMax(&best[b * HALF + s], key);
        }
    }
}

// ---------------- top-k membership + duplicate-dst winner (parallel: 128 blocks) ----------------
__global__ void k_topk(const u64* __restrict__ best, u64* __restrict__ wkey,
                       u32* __restrict__ member, u32* __restrict__ dstmap) {
    __shared__ u32 smono[HALF];
    int b = blockIdx.x >> 4, sc = blockIdx.x & 15;
    int tid = threadIdx.x;
#pragma unroll
    for (int r = 0; r < 8; ++r) { int s = r * 256 + tid; smono[s] = (u32)(best[b * HALF + s] >> 32); }
    __syncthreads();
    int s = sc * 128 + (tid >> 1);
    u32 ms = smono[s];
    int t0 = (tid & 1) * 1024;
    int cnt = 0;
    for (int t = t0; t < t0 + 1024; ++t) {
        u32 mt = smono[t];
        cnt += ((mt > ms) || (mt == ms && t < s)) ? 1 : 0;
    }
    int oth = __shfl_xor(cnt, 1, 64);
    if ((tid & 1) == 0) {
        int rank = cnt + oth;
        u64 k = best[b * HALF + s];
        u32 d = 2047u - (u32)(k & 0xffffffffu);
        dstmap[b * HALF + s] = d;
        u32 mem = (rank < RR) ? 1u : 0u;
        member[b * HALF + s] = mem;
        if (mem) {
            u64 key = (k & 0xffffffff00000000ull) | (u32)(2047 - s);
            atomicMin(&wkey[b * HALF + d], key);   // last-wins: lowest score, then largest s
        }
    }
}

// ---------------- overwrite merged dst rows of xh/xl with split((dst+src)/2) ----------------
__global__ void k_merge2(const float* __restrict__ x, const u64* __restrict__ wkey,
                         f16* __restrict__ xh, f16* __restrict__ xl) {
    int idx = blockIdx.x;
    int b = idx >> 11, d = idx & (HALF - 1);
    u64 wk = wkey[b * HALF + d];
    if (wk == ~0ull) return;
    int s = 2047 - (int)(wk & 0xffffffffu);
    const float* xd = x + ((size_t)b * TOK + 2 * d) * DIM;
    const float* xs = x + ((size_t)b * TOK + 2 * s + 1) * DIM;
    int l0 = threadIdx.x * 8;
    f16x8 h, l;
#pragma unroll
    for (int e = 0; e < 8; ++e) {
        float v = (xd[l0 + e] + xs[l0 + e]) * 0.5f;
        f16 hh = (f16)v;
        h[e] = hh;
        l[e] = (f16)(v - (float)hh);
    }
    size_t off = ((size_t)b * TOK + 2 * d) * DIM + l0;
    *(f16x8*)(xh + off) = h;
    *(f16x8*)(xl + off) = l;
}

// ---------------- y = x_merged @ W + b (fp16 3-term split MFMA) ----------------
__launch_bounds__(256)
__global__ void k_out(const f16* __restrict__ xh, const f16* __restrict__ xl,
                      const f16* __restrict__ Wh, const f16* __restrict__ Wl,
                      const float* __restrict__ bias, float* __restrict__ out) {
    __shared__ f16 As[8][128][8];
    __shared__ f16 Bs[8][128][8];
    int bx = blockIdx.x;
    int im = bx >> 2, in = bx & 3;
    int tid = threadIdx.x, lane = tid & 63, w = tid >> 6, wr = w >> 1, wc = w & 1;
    int cc = lane >> 4, rm = lane & 15;

    f32x4 acc[4][4];
#pragma unroll
    for (int i = 0; i < 4; ++i)
#pragma unroll
        for (int j = 0; j < 4; ++j) acc[i][j] = (f32x4){0.f, 0.f, 0.f, 0.f};

    size_t rowA[4], rowB[4];
#pragma unroll
    for (int r = 0; r < 4; ++r) {
        int g = tid + 256 * r, c = g >> 7, m = g & 127;
        rowA[r] = (size_t)(im * 128 + m) * DIM + c * 8;
        rowB[r] = (size_t)(in * 128 + m) * DIM + c * 8;
    }
    f16x8 pa[4], pb[4];
#pragma unroll
    for (int r = 0; r < 4; ++r) { pa[r] = *(const f16x8*)(xh + rowA[r]); pb[r] = *(const f16x8*)(Wh + rowB[r]); }

    for (int ks = 0; ks < 24; ++ks) {
        __syncthreads();
#pragma unroll
        for (int r = 0; r < 4; ++r) {
            int g = tid + 256 * r;
            *(f16x8*)(&As[0][0][0] + (size_t)g * 8) = pa[r];
            *(f16x8*)(&Bs[0][0][0] + (size_t)g * 8) = pb[r];
        }
        __syncthreads();
        if (ks < 23) {
            int kn = ks + 1, third = kn >> 3, col0 = (kn & 7) << 6;
            const f16* Aa = (third == 1) ? xl : xh;
            const f16* Ba = (third == 2) ? Wl : Wh;
#pragma unroll
            for (int r = 0; r < 4; ++r) {
                pa[r] = *(const f16x8*)(Aa + rowA[r] + col0);
                pb[r] = *(const f16x8*)(Ba + rowB[r] + col0);
            }
        }
#pragma unroll
        for (int kk = 0; kk < 2; ++kk) {
            f16x8 af[4], bf[4];
            int ch = kk * 4 + cc;
#pragma unroll
            for (int f = 0; f < 4; ++f) {
                af[f] = *(const f16x8*)&As[ch][wr * 64 + f * 16 + rm][0];
                bf[f] = *(const f16x8*)&Bs[ch][wc * 64 + f * 16 + rm][0];
            }
#pragma unroll
            for (int i = 0; i < 4; ++i)
#pragma unroll
                for (int j = 0; j < 4; ++j)
                    acc[i][j] = __builtin_amdgcn_mfma_f32_16x16x32_f16(af[i], bf[j], acc[i][j], 0, 0, 0);
        }
    }

    float bj[4];
#pragma unroll
    for (int j = 0; j < 4; ++j) bj[j] = bias[in * 128 + wc * 64 + j * 16 + rm];
#pragma unroll
    for (int i = 0; i < 4; ++i) {
#pragma unroll
        for (int r = 0; r < 4; ++r) {
            int gm = im * 128 + wr * 64 + i * 16 + cc * 4 + r;
#pragma unroll
            for (int j = 0; j < 4; ++j) {
                int n = in * 128 + wc * 64 + j * 16 + rm;
                out[(size_t)gm * DIM + n] = acc[i][j][r] + bj[j];
            }
        }
    }
}

// ---------------- merged src rows copy their dst's hidden row ----------------
__global__ void k_fix(const u32* __restrict__ member, const u32* __restrict__ dstmap,
                      float* __restrict__ out) {
    int idx = blockIdx.x;
    if (!member[idx]) return;
    int b = idx >> 11, s = idx & (HALF - 1);
    const float* sp = out + ((size_t)b * TOK + 2 * (size_t)dstmap[idx]) * DIM;
    float*       dp = out + ((size_t)b * TOK + 2 * (size_t)s + 1) * DIM;
    int l = threadIdx.x;
    *(float4*)(dp + 4 * l) = *(const float4*)(sp + 4 * l);
}

extern "C" void kernel_launch(void* const* d_in, const int* in_sizes, int n_in,
                              void* d_out, int out_size, void* d_ws, size_t ws_size,
                              hipStream_t stream) {
    const float* x    = (const float*)d_in[0];
    const float* W    = (const float*)d_in[1];
    const float* bias = (const float*)d_in[2];
    float* out = (float*)d_out;

    char* ws = (char*)d_ws;
    f16*   xh     = (f16*)(ws);                               // 32 MB
    f16*   xl     = (f16*)(ws + (32u << 20));                 // 32 MB
    f16*   Wh     = (f16*)(ws + (64u << 20));                 // 512 KB
    f16*   Wl     = (f16*)(ws + (64u << 20) + (512u << 10));  // 512 KB
    float* invn   = (float*)(ws + (65u << 20));               // 128 KB
    u64*   best   = (u64*)(ws + (65u << 20) + (128u << 10));  // 128 KB
    u64*   wkey   = (u64*)(ws + (65u << 20) + (256u << 10));  // 128 KB
    u32*   dstmap = (u32*)(ws + (65u << 20) + (384u << 10));  //  64 KB
    u32*   member = (u32*)(ws + (65u << 20) + (448u << 10));  //  64 KB

    hipLaunchKernelGGL(k_init,   dim3(64),    dim3(256), 0, stream, best, wkey);
    hipLaunchKernelGGL(k_split,  dim3(8192),  dim3(256), 0, stream, x, xh, xl);
    hipLaunchKernelGGL(k_wsplit, dim3(512),   dim3(256), 0, stream, W, Wh, Wl);
    hipLaunchKernelGGL(k_norms,  dim3(8192),  dim3(256), 0, stream, x, invn);
    hipLaunchKernelGGL(k_scores, dim3(2048),  dim3(256), 0, stream, xh, xl, invn, best);
    hipLaunchKernelGGL(k_topk,   dim3(128),   dim3(256), 0, stream, best, wkey, member, dstmap);
    hipLaunchKernelGGL(k_merge2, dim3(16384), dim3(64),  0, stream, x, wkey, xh, xl);
    hipLaunchKernelGGL(k_out,    dim3(1024),  dim3(256), 0, stream, xh, xl, Wh, Wl, bias, out);
    hipLaunchKernelGGL(k_fix,    dim3(16384), dim3(128), 0, stream, member, dstmap, out);
}